// Round 13
// baseline (88.292 us; speedup 1.0000x reference)
//
#include <hip/hip_runtime.h>
#include <hip/hip_fp16.h>

// DAS beamforming: out[b,z,x,k] = sum_c lerp(rf[b,c], delay(b,c,z,x))[k]
// Round 18: R5's co-residency geometry + R10's fp16 gather (the one untried
// matrix cell). R11/R13's 2-blocks/CU failures had DIFFERENT chunks
// co-resident (L2 thrash); R5's healthy 2-blocks/CU co-residents shared the
// chunk value and differed only in batch -> rf footprint stays 1 MB/XCD and
// each CU holds TWO independent barrier domains (block A's channel-phase
// drain covered by block B's compute). R5->R10 confounded fp16 with
// 2->1 blocks/CU; this run disentangles.
//  Geometry: THREADS=512, PX=4 (PX_PER_BLOCK=2048, 32 tiles), C_PER_BLOCK=16,
//  8 chunks, grid 512 = 2 blocks/CU (32 KB LDS each), 16 waves/CU,
//  launch_bounds(512,8) caps VGPR at 64. chunk=bid&7=XCD for both
//  co-residents ((bid+256)&7==bid&7); b=bid>>8 differs -> same rf slices
//  per XCD as R10 (1 MB). Staging 268 MB L2-served (R5-proven volume).
//  Kept: fp16-in-LDS via on-the-fly cvt from the CLEAN rf input (never read
//  poisoned ws), 2x16 KB double buffer, T14 async split, NT f32 partials
//  (16.8 MB) + 8-way reduce kernel.

#define NBATCH 2
#define NC 128
#define NS 2048
#define NK 4
#define NM 65536                              // Nz*Nx pixels per batch

#define THREADS 512
#define PX_PER_THREAD 4
#define PX_PER_BLOCK (THREADS * PX_PER_THREAD)   // 2048
#define C_PER_BLOCK 16
#define N_CHUNKS (NC / C_PER_BLOCK)           // 8
#define N_TILES (NM / PX_PER_BLOCK)           // 32
#define NBLOCKS (NBATCH * N_TILES * N_CHUNKS) // 512 = 2 blocks/CU

#define PART_BYTES ((size_t)N_CHUNKS * NBATCH * NM * NK * 4)  // 16.8 MB

typedef float f32x4 __attribute__((ext_vector_type(4)));

// pack 8 f32 -> 8 f16 (one half4 sample pair) for LDS residency
__device__ __forceinline__ uint4 cvt8(float4 a, float4 b) {
    const __half2 h0 = __floats2half2_rn(a.x, a.y);
    const __half2 h1 = __floats2half2_rn(a.z, a.w);
    const __half2 h2 = __floats2half2_rn(b.x, b.y);
    const __half2 h3 = __floats2half2_rn(b.z, b.w);
    return make_uint4(__builtin_bit_cast(unsigned, h0),
                      __builtin_bit_cast(unsigned, h1),
                      __builtin_bit_cast(unsigned, h2),
                      __builtin_bit_cast(unsigned, h3));
}

template <bool ATOMIC>
__global__ __launch_bounds__(THREADS, 8) void das_kernel(
    const float* __restrict__ rf, const float* __restrict__ g,
    const float* __restrict__ pr, const float* __restrict__ p,
    float* __restrict__ dst)    // ATOMIC ? out : partials in ws
{
    __shared__ uint4 sbuf[2][NS / 2];   // 2 x 16 KiB fp16 double buffer

    const int bid   = blockIdx.x;
    const int chunk = bid & (N_CHUNKS - 1);          // == XCD id; co-resident
    const int tile  = (bid >> 3) & (N_TILES - 1);    //   blocks share chunk
    const int b     = bid >> 8;                      //   and differ in batch
    const int t     = threadIdx.x;
    const int px0   = tile * PX_PER_BLOCK;

    const float c0v = p[b * 4 + 0];
    const float fsv = p[b * 4 + 1];
    const float t0v = p[b * 4 + 2];
    const float scale = fsv / c0v;            // samples per meter
    const float sb0   = scale * t0v;

    float gx[PX_PER_THREAD], gy[PX_PER_THREAD], gzv[PX_PER_THREAD];
#pragma unroll
    for (int j = 0; j < PX_PER_THREAD; ++j) {
        const int m = px0 + j * THREADS + t;
        const float* gp = g + ((size_t)b * NM + m) * 3;
        gx[j]  = gp[0];
        gy[j]  = gp[1];
        gzv[j] = gp[2];
    }

    float4 acc[PX_PER_THREAD];
#pragma unroll
    for (int j = 0; j < PX_PER_THREAD; ++j) acc[j] = make_float4(0.f, 0.f, 0.f, 0.f);

    const int ch0 = chunk * C_PER_BLOCK;
    const float* slice0 = rf + (size_t)(b * NC + ch0) * NS * NK;

    // initial stage: slice 0 -> regs -> fp16 -> buf0. 512 threads x 2 uint4:
    // thread t owns slots t and t+512 (wave-contiguous 16 B each).
    {
        const float4* s4 = (const float4*)slice0;
        const float4 a0 = s4[2 * t];
        const float4 a1 = s4[2 * t + 1];
        const float4 b0 = s4[2 * (t + THREADS)];
        const float4 b1 = s4[2 * (t + THREADS) + 1];
        sbuf[0][t]           = cvt8(a0, a1);
        sbuf[0][t + THREADS] = cvt8(b0, b1);
    }

    for (int cc = 0; cc < C_PER_BLOCK; ++cc) {
        // barrier publishes buf (cc&1) writes from the previous iteration and
        // guarantees everyone finished reading buf ((cc+1)&1) two iters ago.
        // The co-resident block (other batch, same chunk) computes through
        // this drain — two independent barrier domains per CU.
        __syncthreads();

        // T14 async split: issue next slice's global loads NOW; the vmcnt
        // drain + cvt + ds_write happen after this iteration's compute.
        float4 a0, a1, b0, b1;
        if (cc + 1 < C_PER_BLOCK) {
            const float4* s4 = (const float4*)(slice0 + (size_t)(cc + 1) * NS * NK);
            a0 = s4[2 * t];
            a1 = s4[2 * t + 1];
            b0 = s4[2 * (t + THREADS)];
            b1 = s4[2 * (t + THREADS) + 1];
        }

        const uint2* lb = (const uint2*)&sbuf[cc & 1][0];   // half4 samples
        const float* prp = pr + ((size_t)(b * NC + ch0 + cc)) * 3;
        const float prx = prp[0], pry = prp[1], prz = prp[2];

#pragma unroll
        for (int j = 0; j < PX_PER_THREAD; ++j) {
            const float dx = gx[j]  - prx;
            const float dy = gy[j]  - pry;
            const float dz = gzv[j] - prz;
            const float drx = __builtin_amdgcn_sqrtf(fmaf(dx, dx, fmaf(dy, dy, dz * dz)));
            float s = fmaf(scale, gzv[j] + drx, sb0);      // fs*(t0+gz+drx)/c0
            s = fminf(fmaxf(s, 0.0f), (float)(NS - 1));    // clamp
            const float fi = fminf(floorf(s), (float)(NS - 2));
            const float w  = s - fi;
            const float wm = 1.0f - w;
            const int i0 = (int)fi;
            const uint2 u0 = lb[i0];          // half4 y0 | contiguous 16 B:
            const uint2 u1 = lb[i0 + 1];      // half4 y1 | one ds_read2_b64
            const float2 y0a = __half22float2(__builtin_bit_cast(__half2, u0.x));
            const float2 y0b = __half22float2(__builtin_bit_cast(__half2, u0.y));
            const float2 y1a = __half22float2(__builtin_bit_cast(__half2, u1.x));
            const float2 y1b = __half22float2(__builtin_bit_cast(__half2, u1.y));
            acc[j].x = fmaf(y0a.x, wm, fmaf(y1a.x, w, acc[j].x));
            acc[j].y = fmaf(y0a.y, wm, fmaf(y1a.y, w, acc[j].y));
            acc[j].z = fmaf(y0b.x, wm, fmaf(y1b.x, w, acc[j].z));
            acc[j].w = fmaf(y0b.y, wm, fmaf(y1b.y, w, acc[j].w));
        }

        // drain the prefetch (s_waitcnt auto-inserted), convert, publish on
        // the NEXT barrier. Writing buf ((cc+1)&1) is safe: all waves passed
        // the barrier above, so nobody still reads it from iteration cc-1.
        if (cc + 1 < C_PER_BLOCK) {
            sbuf[(cc + 1) & 1][t]           = cvt8(a0, a1);
            sbuf[(cc + 1) & 1][t + THREADS] = cvt8(b0, b1);
        }
    }

    if (ATOMIC) {
        float* ob = dst + (size_t)b * NM * NK;
#pragma unroll
        for (int j = 0; j < PX_PER_THREAD; ++j) {
            const int m = px0 + j * THREADS + t;
            float* op = ob + (size_t)m * NK;
            atomicAdd(op + 0, acc[j].x);
            atomicAdd(op + 1, acc[j].y);
            atomicAdd(op + 2, acc[j].z);
            atomicAdd(op + 3, acc[j].w);
        }
    } else {
        // partial[chunk][b][m] — disjoint per block. NON-TEMPORAL: write-once
        // data must not allocate in L2/LLC (evicts rf + dirty poison lines).
        f32x4* pw = (f32x4*)dst + (size_t)(chunk * NBATCH + b) * NM;
#pragma unroll
        for (int j = 0; j < PX_PER_THREAD; ++j) {
            const int m = px0 + j * THREADS + t;
            const f32x4 v = {acc[j].x, acc[j].y, acc[j].z, acc[j].w};
            __builtin_nontemporal_store(v, pw + m);
        }
    }
}

// out[i] = sum over 8 chunk partials; i indexes float4 over [B*NM)
__global__ __launch_bounds__(256) void reduce_kernel(
    const f32x4* __restrict__ part, f32x4* __restrict__ out)
{
    const int i = blockIdx.x * 256 + threadIdx.x;
    const size_t stride = (size_t)NBATCH * NM;
    f32x4 a = __builtin_nontemporal_load(part + i);
#pragma unroll
    for (int c = 1; c < N_CHUNKS; ++c) {
        const f32x4 v = __builtin_nontemporal_load(part + c * stride + i);
        a += v;
    }
    out[i] = a;
}

extern "C" void kernel_launch(void* const* d_in, const int* in_sizes, int n_in,
                              void* d_out, int out_size, void* d_ws, size_t ws_size,
                              hipStream_t stream) {
    (void)in_sizes; (void)n_in;
    const float* rf = (const float*)d_in[0];
    const float* g  = (const float*)d_in[1];
    const float* pr = (const float*)d_in[2];
    const float* p  = (const float*)d_in[3];
    float* out = (float*)d_out;

    if (ws_size >= PART_BYTES) {
        das_kernel<false><<<NBLOCKS, THREADS, 0, stream>>>(rf, g, pr, p, (float*)d_ws);
        reduce_kernel<<<(NBATCH * NM) / 256, 256, 0, stream>>>((const f32x4*)d_ws,
                                                               (f32x4*)out);
    } else {
        (void)hipMemsetAsync(d_out, 0, (size_t)out_size * sizeof(float), stream);
        das_kernel<true><<<NBLOCKS, THREADS, 0, stream>>>(rf, g, pr, p, out);
    }
}

// Round 14
// 86.770 us; speedup vs baseline: 1.0175x; 1.0175x over previous
//
#include <hip/hip_runtime.h>
#include <hip/hip_fp16.h>

// DAS beamforming: out[b,z,x,k] = sum_c lerp(rf[b,c], delay(b,c,z,x))[k]
// Round 19: FINAL revert to the session optimum (R10, reproduced twice:
// 86.97 / 87.40 us). R18 closed the last untried matrix cell (same-chunk
// co-residency + fp16): 88.29 us, no gain.
//  Thirteen structural probes bracket das at ~36-40 us (latency floor of the
//  random-gather + per-channel-phase structure); the timed window is
//  41.4 us harness ws-poison fill (HBM-saturated, unavoidable, 48%) +
//  ~38 us das + ~3 us reduce + ~3-4 us gaps = 86-88 us structural ceiling.
//  Structure: fp16-in-LDS, on-the-fly conversion from the CLEAN rf input
//  (never read poisoned ws), 2 x 16 KiB double buffer, T14 async split,
//  256 blocks = 2 batch x 16 tiles x 8 chunks (chunk=bid&7 pins chunk<->XCD,
//  rf footprint 1 MB/L2), 1 block/CU, NT f32 partials + reduce kernel.
//  Known-fatal variants (do NOT revisit): staging rf through ws (R6: poison
//  -dirty LLC -> 380 MB HBM), cross-XCD chunk co-residency (R11/R13: L2
//  thrash, 200+ MB fetch), device-fence grid fusion (R15: 204 us), contended
//  out atomics (R4: 8-way XCD line ping-pong).

#define NBATCH 2
#define NC 128
#define NS 2048
#define NK 4
#define NM 65536                              // Nz*Nx pixels per batch

#define THREADS 1024
#define PX_PER_THREAD 4
#define PX_PER_BLOCK (THREADS * PX_PER_THREAD)   // 4096
#define C_PER_BLOCK 16
#define N_CHUNKS (NC / C_PER_BLOCK)           // 8
#define N_TILES (NM / PX_PER_BLOCK)           // 16
#define NBLOCKS (NBATCH * N_TILES * N_CHUNKS) // 256 = 1 block/CU

#define PART_BYTES ((size_t)N_CHUNKS * NBATCH * NM * NK * 4)  // 16.8 MB

typedef float f32x4 __attribute__((ext_vector_type(4)));

// pack 8 f32 -> 8 f16 (one half4 sample pair) for LDS residency
__device__ __forceinline__ uint4 cvt8(float4 a, float4 b) {
    const __half2 h0 = __floats2half2_rn(a.x, a.y);
    const __half2 h1 = __floats2half2_rn(a.z, a.w);
    const __half2 h2 = __floats2half2_rn(b.x, b.y);
    const __half2 h3 = __floats2half2_rn(b.z, b.w);
    return make_uint4(__builtin_bit_cast(unsigned, h0),
                      __builtin_bit_cast(unsigned, h1),
                      __builtin_bit_cast(unsigned, h2),
                      __builtin_bit_cast(unsigned, h3));
}

template <bool ATOMIC>
__global__ __launch_bounds__(THREADS, 4) void das_kernel(
    const float* __restrict__ rf, const float* __restrict__ g,
    const float* __restrict__ pr, const float* __restrict__ p,
    float* __restrict__ dst)    // ATOMIC ? out : partials in ws
{
    __shared__ uint4 sbuf[2][NS / 2];   // 2 x 16 KiB fp16 double buffer

    const int bid   = blockIdx.x;
    const int chunk = bid & (N_CHUNKS - 1);          // chunk&7 == XCD id
    const int tile  = (bid >> 3) & (N_TILES - 1);
    const int b     = bid >> 7;
    const int t     = threadIdx.x;
    const int px0   = tile * PX_PER_BLOCK;

    const float c0v = p[b * 4 + 0];
    const float fsv = p[b * 4 + 1];
    const float t0v = p[b * 4 + 2];
    const float scale = fsv / c0v;            // samples per meter
    const float sb0   = scale * t0v;

    float gx[PX_PER_THREAD], gy[PX_PER_THREAD], gzv[PX_PER_THREAD];
#pragma unroll
    for (int j = 0; j < PX_PER_THREAD; ++j) {
        const int m = px0 + j * THREADS + t;
        const float* gp = g + ((size_t)b * NM + m) * 3;
        gx[j]  = gp[0];
        gy[j]  = gp[1];
        gzv[j] = gp[2];
    }

    float4 acc[PX_PER_THREAD];
#pragma unroll
    for (int j = 0; j < PX_PER_THREAD; ++j) acc[j] = make_float4(0.f, 0.f, 0.f, 0.f);

    const int ch0 = chunk * C_PER_BLOCK;
    const float* slice0 = rf + (size_t)(b * NC + ch0) * NS * NK;

    // initial stage: slice 0 -> regs -> fp16 -> buf0 (thread t owns slot t)
    {
        const float4* s4 = (const float4*)slice0;
        const float4 a0 = s4[2 * t];
        const float4 a1 = s4[2 * t + 1];
        sbuf[0][t] = cvt8(a0, a1);
    }

    for (int cc = 0; cc < C_PER_BLOCK; ++cc) {
        // barrier publishes buf (cc&1) writes from the previous iteration and
        // guarantees everyone finished reading buf ((cc+1)&1) two iters ago.
        __syncthreads();

        // T14 async split: issue next slice's global loads NOW; the vmcnt
        // drain + cvt + ds_write happen after this iteration's compute.
        float4 a0, a1;
        if (cc + 1 < C_PER_BLOCK) {
            const float4* s4 = (const float4*)(slice0 + (size_t)(cc + 1) * NS * NK);
            a0 = s4[2 * t];
            a1 = s4[2 * t + 1];
        }

        const uint2* lb = (const uint2*)&sbuf[cc & 1][0];   // half4 samples
        const float* prp = pr + ((size_t)(b * NC + ch0 + cc)) * 3;
        const float prx = prp[0], pry = prp[1], prz = prp[2];

#pragma unroll
        for (int j = 0; j < PX_PER_THREAD; ++j) {
            const float dx = gx[j]  - prx;
            const float dy = gy[j]  - pry;
            const float dz = gzv[j] - prz;
            const float drx = __builtin_amdgcn_sqrtf(fmaf(dx, dx, fmaf(dy, dy, dz * dz)));
            float s = fmaf(scale, gzv[j] + drx, sb0);      // fs*(t0+gz+drx)/c0
            s = fminf(fmaxf(s, 0.0f), (float)(NS - 1));    // clamp
            const float fi = fminf(floorf(s), (float)(NS - 2));
            const float w  = s - fi;
            const float wm = 1.0f - w;
            const int i0 = (int)fi;
            const uint2 u0 = lb[i0];          // half4 y0 | contiguous 16 B:
            const uint2 u1 = lb[i0 + 1];      // half4 y1 | one ds_read2_b64
            const float2 y0a = __half22float2(__builtin_bit_cast(__half2, u0.x));
            const float2 y0b = __half22float2(__builtin_bit_cast(__half2, u0.y));
            const float2 y1a = __half22float2(__builtin_bit_cast(__half2, u1.x));
            const float2 y1b = __half22float2(__builtin_bit_cast(__half2, u1.y));
            acc[j].x = fmaf(y0a.x, wm, fmaf(y1a.x, w, acc[j].x));
            acc[j].y = fmaf(y0a.y, wm, fmaf(y1a.y, w, acc[j].y));
            acc[j].z = fmaf(y0b.x, wm, fmaf(y1b.x, w, acc[j].z));
            acc[j].w = fmaf(y0b.y, wm, fmaf(y1b.y, w, acc[j].w));
        }

        // drain the prefetch (s_waitcnt auto-inserted), convert, publish on
        // the NEXT barrier. Writing buf ((cc+1)&1) is safe: all waves passed
        // the barrier above, so nobody still reads it from iteration cc-1.
        if (cc + 1 < C_PER_BLOCK)
            sbuf[(cc + 1) & 1][t] = cvt8(a0, a1);
    }

    if (ATOMIC) {
        float* ob = dst + (size_t)b * NM * NK;
#pragma unroll
        for (int j = 0; j < PX_PER_THREAD; ++j) {
            const int m = px0 + j * THREADS + t;
            float* op = ob + (size_t)m * NK;
            atomicAdd(op + 0, acc[j].x);
            atomicAdd(op + 1, acc[j].y);
            atomicAdd(op + 2, acc[j].z);
            atomicAdd(op + 3, acc[j].w);
        }
    } else {
        // partial[chunk][b][m] — disjoint per block. NON-TEMPORAL: write-once
        // data must not allocate in L2/LLC (evicts rf + dirty poison lines).
        f32x4* pw = (f32x4*)dst + (size_t)(chunk * NBATCH + b) * NM;
#pragma unroll
        for (int j = 0; j < PX_PER_THREAD; ++j) {
            const int m = px0 + j * THREADS + t;
            const f32x4 v = {acc[j].x, acc[j].y, acc[j].z, acc[j].w};
            __builtin_nontemporal_store(v, pw + m);
        }
    }
}

// out[i] = sum over 8 chunk partials; i indexes float4 over [B*NM)
__global__ __launch_bounds__(256) void reduce_kernel(
    const f32x4* __restrict__ part, f32x4* __restrict__ out)
{
    const int i = blockIdx.x * 256 + threadIdx.x;
    const size_t stride = (size_t)NBATCH * NM;
    f32x4 a = __builtin_nontemporal_load(part + i);
#pragma unroll
    for (int c = 1; c < N_CHUNKS; ++c) {
        const f32x4 v = __builtin_nontemporal_load(part + c * stride + i);
        a += v;
    }
    out[i] = a;
}

extern "C" void kernel_launch(void* const* d_in, const int* in_sizes, int n_in,
                              void* d_out, int out_size, void* d_ws, size_t ws_size,
                              hipStream_t stream) {
    (void)in_sizes; (void)n_in;
    const float* rf = (const float*)d_in[0];
    const float* g  = (const float*)d_in[1];
    const float* pr = (const float*)d_in[2];
    const float* p  = (const float*)d_in[3];
    float* out = (float*)d_out;

    if (ws_size >= PART_BYTES) {
        das_kernel<false><<<NBLOCKS, THREADS, 0, stream>>>(rf, g, pr, p, (float*)d_ws);
        reduce_kernel<<<(NBATCH * NM) / 256, 256, 0, stream>>>((const f32x4*)d_ws,
                                                               (f32x4*)out);
    } else {
        (void)hipMemsetAsync(d_out, 0, (size_t)out_size * sizeof(float), stream);
        das_kernel<true><<<NBLOCKS, THREADS, 0, stream>>>(rf, g, pr, p, out);
    }
}